// Round 1
// baseline (974.947 us; speedup 1.0000x reference)
//
#include <hip/hip_runtime.h>

typedef unsigned short u16;
using bf16x8 = __attribute__((ext_vector_type(8))) __bf16;
using f32x4  = __attribute__((ext_vector_type(4))) float;
using u16x8  = __attribute__((ext_vector_type(8))) u16;

__device__ __forceinline__ u16 f2bf(float f) {
    unsigned u = __builtin_bit_cast(unsigned, f);
    u += 0x7FFFu + ((u >> 16) & 1u);           // round-to-nearest-even
    return (u16)(u >> 16);
}
__device__ __forceinline__ float bf2f(u16 h) {
    unsigned u = ((unsigned)h) << 16;
    return __builtin_bit_cast(float, u);
}
__device__ __forceinline__ u16 to_bf(float f) { return f2bf(f); }
__device__ __forceinline__ u16 to_bf(u16 h)   { return h; }

// async global->LDS, 16B per lane; LDS base must be wave-uniform.
__device__ __forceinline__ void gload_lds16(const u16* g, u16* l) {
    __builtin_amdgcn_global_load_lds(
        (const __attribute__((address_space(1))) unsigned int*)g,
        (__attribute__((address_space(3))) unsigned int*)l,
        16, 0, 0);
}

// ---------------- fp32 -> bf16 elementwise (vectorized) ----------------
__global__ __launch_bounds__(256) void k_cvt_f32_bf16(const float* __restrict__ in,
                                                      u16* __restrict__ out, long n) {
    long i = ((long)blockIdx.x * 256 + threadIdx.x) * 8;
    if (i + 8 > n) return;
    f32x4 a = *(const f32x4*)(in + i);
    f32x4 b = *(const f32x4*)(in + i + 4);
    u16x8 o;
    o[0] = f2bf(a[0]); o[1] = f2bf(a[1]); o[2] = f2bf(a[2]); o[3] = f2bf(a[3]);
    o[4] = f2bf(b[0]); o[5] = f2bf(b[1]); o[6] = f2bf(b[2]); o[7] = f2bf(b[3]);
    *(u16x8*)(out + i) = o;
}

// ---------------- tiled transpose (f32->bf16 or bf16->bf16) ----------------
// in: [R][C] (row stride in_rs), out: [C][R] (row stride out_rs), batched via z
template <typename T>
__global__ __launch_bounds__(256) void k_transpose_bf16(
    const T* __restrict__ in, long in_rs, long in_bs,
    u16* __restrict__ out, long out_rs, long out_bs, int R, int C) {
    __shared__ u16 tile[32][33];
    const int b = blockIdx.z;
    const T* ip = in + (long)b * in_bs;
    u16* op = out + (long)b * out_bs;
    const int tx = threadIdx.x, ty = threadIdx.y;
    const long r0 = (long)blockIdx.y * 32, c0 = (long)blockIdx.x * 32;
#pragma unroll
    for (int i = 0; i < 4; ++i) {
        int r = ty + i * 8;
        tile[r][tx] = to_bf(ip[(r0 + r) * in_rs + c0 + tx]);
    }
    __syncthreads();
#pragma unroll
    for (int i = 0; i < 4; ++i) {
        int c = ty + i * 8;
        op[(c0 + c) * out_rs + r0 + tx] = tile[tx][c];
    }
}

// ---------------- row sum of exp-probs -> reciprocal ----------------
__global__ __launch_bounds__(256) void k_rowsum_recip(const u16* __restrict__ P,
                                                      float* __restrict__ out, int C) {
    const long row = blockIdx.x;
    const u16* p = P + row * (long)C;
    float s = 0.f;
    for (int c = threadIdx.x * 8; c < C; c += 256 * 8) {
        u16x8 v = *(const u16x8*)(p + c);
#pragma unroll
        for (int j = 0; j < 8; ++j) s += bf2f(v[j]);
    }
#pragma unroll
    for (int off = 32; off > 0; off >>= 1) s += __shfl_down(s, off);
    __shared__ float wsum[4];
    const int lane = threadIdx.x & 63, wid = threadIdx.x >> 6;
    if (lane == 0) wsum[wid] = s;
    __syncthreads();
    if (threadIdx.x == 0) out[row] = 1.0f / (wsum[0] + wsum[1] + wsum[2] + wsum[3]);
}

// ---------------- 128x128 bf16 GEMM, C = A * B^T, templated epilogue ----------------
// A: [M][K] (lda), B: [N][K] (ldb), both bf16(u16). M,N multiples of 128, K of 64.
// EPI 0: C=bf16(acc)   1: C=bf16(exp(acc*scale))   2: C=bf16(acc*rrow[row])
// EPI 3: C=f32(acc + bias[col])
template <int EPI>
__global__ __launch_bounds__(256) void k_gemm_bt(
    const u16* __restrict__ A, long lda,
    const u16* __restrict__ B, long ldb,
    void* __restrict__ Cv, long ldc, int K, float scale,
    const float* __restrict__ rrow, const float* __restrict__ bias) {
    __shared__ __align__(16) u16 As[128 * 64];
    __shared__ __align__(16) u16 Bs[128 * 64];
    const int tid = threadIdx.x;
    const int lane = tid & 63;
    const int wid = tid >> 6;
    const int wr = wid >> 1, wc = wid & 1;   // 2x2 wave grid, 64x64 per wave
    const long m0 = (long)blockIdx.y * 128;
    const long n0 = (long)blockIdx.x * 128;

    f32x4 acc[4][4] = {};

    for (int kt = 0; kt < K; kt += 64) {
        __syncthreads();
#pragma unroll
        for (int i = 0; i < 4; ++i) {
            const int s = i * 4 + wid;               // 16 segments of 512 elems
            const int flat = s * 512 + lane * 8;     // elem index in [128][64] tile
            const int r = flat >> 6, c = flat & 63;
            gload_lds16(A + (m0 + r) * lda + kt + c, &As[s * 512]);
            gload_lds16(B + (n0 + r) * ldb + kt + c, &Bs[s * 512]);
        }
        __syncthreads();
#pragma unroll
        for (int ks = 0; ks < 2; ++ks) {
            bf16x8 af[4], bfr[4];
#pragma unroll
            for (int m = 0; m < 4; ++m)
                af[m] = *(const bf16x8*)(&As[(wr * 64 + m * 16 + (lane & 15)) * 64 +
                                             ks * 32 + (lane >> 4) * 8]);
#pragma unroll
            for (int n = 0; n < 4; ++n)
                bfr[n] = *(const bf16x8*)(&Bs[(wc * 64 + n * 16 + (lane & 15)) * 64 +
                                              ks * 32 + (lane >> 4) * 8]);
#pragma unroll
            for (int m = 0; m < 4; ++m)
#pragma unroll
                for (int n = 0; n < 4; ++n)
                    acc[m][n] = __builtin_amdgcn_mfma_f32_16x16x32_bf16(
                        af[m], bfr[n], acc[m][n], 0, 0, 0);
        }
    }

    // C/D layout (m89-verified): col = lane&15, row = (lane>>4)*4 + reg
    const int r_in = (lane >> 4) * 4;
    const int c_in = lane & 15;
#pragma unroll
    for (int m = 0; m < 4; ++m) {
#pragma unroll
        for (int n = 0; n < 4; ++n) {
            const long cg = n0 + wc * 64 + n * 16 + c_in;
#pragma unroll
            for (int j = 0; j < 4; ++j) {
                const long rg = m0 + wr * 64 + m * 16 + r_in + j;
                float v = acc[m][n][j];
                if constexpr (EPI == 0) {
                    ((u16*)Cv)[rg * ldc + cg] = f2bf(v);
                } else if constexpr (EPI == 1) {
                    ((u16*)Cv)[rg * ldc + cg] = f2bf(__expf(v * scale));
                } else if constexpr (EPI == 2) {
                    ((u16*)Cv)[rg * ldc + cg] = f2bf(v * rrow[rg]);
                } else {
                    ((float*)Cv)[rg * ldc + cg] = v + bias[cg];
                }
            }
        }
    }
}

extern "C" void kernel_launch(void* const* d_in, const int* in_sizes, int n_in,
                              void* d_out, int out_size, void* d_ws, size_t ws_size,
                              hipStream_t stream) {
    (void)in_sizes; (void)n_in; (void)out_size; (void)ws_size;
    const int S = 4096;
    const long BS = 4L * S;  // 16384 tokens
    const float* x_f    = (const float*)d_in[0];  // [BS][2048]
    const float* Wqkv_f = (const float*)d_in[1];  // [2048][3072]
    const float* Wff_f  = (const float*)d_in[2];  // [1024][1024]
    const float* bff    = (const float*)d_in[3];  // [1024]
    float* out = (float*)d_out;                   // [BS][1024]

    char* p = (char*)d_ws;
    u16* x_bf  = (u16*)p; p += BS * 2048 * 2;            // 67.1 MB
    u16* WqkvT = (u16*)p; p += 3072L * 2048 * 2;         // 12.6 MB  [3072][2048]
    u16* WffT  = (u16*)p; p += 1024L * 1024 * 2;         //  2.1 MB  [1024][1024]
    u16* kqv   = (u16*)p; p += BS * 3072 * 2;            // 100.7 MB [BS][3072] (k|q|v)
    u16* vT    = (u16*)p; p += 4L * 1024 * 4096 * 2;     // 33.6 MB  [4][1024][4096]
    u16* probs = (u16*)p; p += 4096L * 4096 * 2;         // 33.6 MB  per-batch reuse
    u16* attn  = (u16*)p; p += BS * 1024 * 2;            // 33.6 MB  [BS][1024]
    float* rrow = (float*)p; p += 4096L * 4;             // 16 KB

    // 1. input & weight conversion / transposition
    k_cvt_f32_bf16<<<dim3((unsigned)(BS * 2048 / 2048)), 256, 0, stream>>>(x_f, x_bf, BS * 2048);
    k_transpose_bf16<float><<<dim3(3072 / 32, 2048 / 32, 1), dim3(32, 8), 0, stream>>>(
        Wqkv_f, 3072, 0, WqkvT, 2048, 0, 2048, 3072);
    k_transpose_bf16<float><<<dim3(1024 / 32, 1024 / 32, 1), dim3(32, 8), 0, stream>>>(
        Wff_f, 1024, 0, WffT, 1024, 0, 1024, 1024);

    // 2. kqv = X @ W_qkv   [16384 x 3072], K=2048
    k_gemm_bt<0><<<dim3(3072 / 128, 16384 / 128), 256, 0, stream>>>(
        x_bf, 2048, WqkvT, 2048, kqv, 3072, 2048, 0.f, nullptr, nullptr);

    // 3. transpose V (cols [2048,3072) of kqv) to [4][1024][4096]
    k_transpose_bf16<u16><<<dim3(1024 / 32, 4096 / 32, 4), dim3(32, 8), 0, stream>>>(
        kqv + 2048, 3072, (long)S * 3072, vT, 4096, 1024L * 4096, 4096, 1024);

    // 4. attention per batch: probs = exp(Q K^T * scale); out = (probs @ V) / rowsum
    const float scale = 0.08838834764831845f;  // 1/sqrt(128)
    for (int b = 0; b < 4; ++b) {
        const u16* kbase = kqv + (long)b * S * 3072;  // k at +0, q at +1024
        k_gemm_bt<1><<<dim3(32, 32), 256, 0, stream>>>(
            kbase + 1024, 3072, kbase, 3072, probs, 4096, 1024, scale, nullptr, nullptr);
        k_rowsum_recip<<<4096, 256, 0, stream>>>(probs, rrow, 4096);
        k_gemm_bt<2><<<dim3(8, 32), 256, 0, stream>>>(
            probs, 4096, vT + (long)b * 1024 * 4096, 4096,
            attn + (long)b * S * 1024, 1024, 4096, 0.f, rrow, nullptr);
    }

    // 5. out = attn @ W_ff + b_ff  (fp32 output)
    k_gemm_bt<3><<<dim3(8, 128), 256, 0, stream>>>(
        attn, 1024, WffT, 1024, out, 1024, 1024, 0.f, nullptr, bff);
}

// Round 3
// 741.995 us; speedup vs baseline: 1.3140x; 1.3140x over previous
//
#include <hip/hip_runtime.h>

typedef unsigned short u16;
using bf16x8 = __attribute__((ext_vector_type(8))) __bf16;
using f32x4  = __attribute__((ext_vector_type(4))) float;
using u16x8  = __attribute__((ext_vector_type(8))) u16;

__device__ __forceinline__ u16 f2bf(float f) {
    unsigned u = __builtin_bit_cast(unsigned, f);
    u += 0x7FFFu + ((u >> 16) & 1u);           // round-to-nearest-even
    return (u16)(u >> 16);
}
__device__ __forceinline__ float bf2f(u16 h) {
    unsigned u = ((unsigned)h) << 16;
    return __builtin_bit_cast(float, u);
}
__device__ __forceinline__ u16 to_bf(float f) { return f2bf(f); }
__device__ __forceinline__ u16 to_bf(u16 h)   { return h; }

// async global->LDS, 16B per lane; LDS base must be wave-uniform.
__device__ __forceinline__ void gload_lds16(const u16* g, u16* l) {
    __builtin_amdgcn_global_load_lds(
        (const __attribute__((address_space(1))) unsigned int*)g,
        (__attribute__((address_space(3))) unsigned int*)l,
        16, 0, 0);
}

// ---------------- fp32 -> bf16 elementwise (vectorized) ----------------
__global__ __launch_bounds__(256) void k_cvt_f32_bf16(const float* __restrict__ in,
                                                      u16* __restrict__ out, long n) {
    long i = ((long)blockIdx.x * 256 + threadIdx.x) * 8;
    if (i + 8 > n) return;
    f32x4 a = *(const f32x4*)(in + i);
    f32x4 b = *(const f32x4*)(in + i + 4);
    u16x8 o;
    o[0] = f2bf(a[0]); o[1] = f2bf(a[1]); o[2] = f2bf(a[2]); o[3] = f2bf(a[3]);
    o[4] = f2bf(b[0]); o[5] = f2bf(b[1]); o[6] = f2bf(b[2]); o[7] = f2bf(b[3]);
    *(u16x8*)(out + i) = o;
}

// ---------------- tiled transpose (f32->bf16 or bf16->bf16) ----------------
template <typename T>
__global__ __launch_bounds__(256) void k_transpose_bf16(
    const T* __restrict__ in, long in_rs, long in_bs,
    u16* __restrict__ out, long out_rs, long out_bs, int R, int C) {
    __shared__ u16 tile[32][33];
    const int b = blockIdx.z;
    const T* ip = in + (long)b * in_bs;
    u16* op = out + (long)b * out_bs;
    const int tx = threadIdx.x, ty = threadIdx.y;
    const long r0 = (long)blockIdx.y * 32, c0 = (long)blockIdx.x * 32;
#pragma unroll
    for (int i = 0; i < 4; ++i) {
        int r = ty + i * 8;
        tile[r][tx] = to_bf(ip[(r0 + r) * in_rs + c0 + tx]);
    }
    __syncthreads();
#pragma unroll
    for (int i = 0; i < 4; ++i) {
        int c = ty + i * 8;
        op[(c0 + c) * out_rs + r0 + tx] = tile[tx][c];
    }
}

// ---------------- row sum of exp-probs -> reciprocal ----------------
__global__ __launch_bounds__(256) void k_rowsum_recip(const u16* __restrict__ P,
                                                      float* __restrict__ out, int C) {
    const long row = blockIdx.x;
    const u16* p = P + row * (long)C;
    float s = 0.f;
    for (int c = threadIdx.x * 8; c < C; c += 256 * 8) {
        u16x8 v = *(const u16x8*)(p + c);
#pragma unroll
        for (int j = 0; j < 8; ++j) s += bf2f(v[j]);
    }
#pragma unroll
    for (int off = 32; off > 0; off >>= 1) s += __shfl_down(s, off);
    __shared__ float wsum[4];
    const int lane = threadIdx.x & 63, wid = threadIdx.x >> 6;
    if (lane == 0) wsum[wid] = s;
    __syncthreads();
    if (threadIdx.x == 0) out[row] = 1.0f / (wsum[0] + wsum[1] + wsum[2] + wsum[3]);
}

// ================= 256x256 8-phase bf16 GEMM, C = A * B^T =================
// A: [M][K] (lda), B: [N][K] (ldb). M,N multiples of 256, K of 64.
// LDS: [2 buf][2 ksub][256 r][32 k] per operand, st_16x32 swizzle
// (byte ^= ((byte>>9)&1)<<5), applied on pre-swizzled global src + ds_read.
// Phases per K-tile: (k0,m0-3) (k0,m4-7) (k1,m0-3) (k1,m4-7), each staging one
// 16KB unit of tile t+1; counted vmcnt(4) at end of phases B and D.
// EPI 0: bf16(acc)  1: bf16(exp(acc*scale))  2: bf16(acc*rrow[row])  3: f32(acc+bias[col])

#define LGK0 asm volatile("s_waitcnt lgkmcnt(0)" ::: "memory")
#define VM4  asm volatile("s_waitcnt vmcnt(4)" ::: "memory")
#define VM0  asm volatile("s_waitcnt vmcnt(0)" ::: "memory")
#define SCHB __builtin_amdgcn_sched_barrier(0)
#define BAR  __builtin_amdgcn_s_barrier()

template <int EPI>
__global__ __launch_bounds__(512, 2) void k_gemm8(
    const u16* __restrict__ Ag, long lda, long sA,
    const u16* __restrict__ Bg, long ldb, long sB,
    void* __restrict__ Cv, long ldc, long sC,
    int K, float scale, const float* __restrict__ rrowZ, long sR,
    const float* __restrict__ bias) {
    __shared__ __align__(16) u16 As[2][2][256 * 32];
    __shared__ __align__(16) u16 Bs[2][2][256 * 32];

    const int tid = threadIdx.x;
    const int lane = tid & 63, wid = tid >> 6;
    const int wm = wid >> 2, wn = wid & 3;   // 2(M) x 4(N) wave grid
    const int z = blockIdx.z;
    const long m0 = (long)blockIdx.y * 256;
    const long n0 = (long)blockIdx.x * 256;
    const u16* A = Ag + (long)z * sA;
    const u16* B = Bg + (long)z * sB;

    // staging map: LDS dest is linear (unit + (wid*2+c)*1024B + lane*16B);
    // global src pre-swizzled so swizzled reads see logical [r][k].
    int st_idx[2]; long aRow[2], bRow[2];
#pragma unroll
    for (int c = 0; c < 2; ++c) {
        int d_lin = (wid * 2 + c) * 1024 + lane * 16;
        int d_log = d_lin ^ (((d_lin >> 9) & 1) << 5);
        int r = d_log >> 6, kk = (d_log & 63) >> 1;
        st_idx[c] = (wid * 2 + c) * 512;
        aRow[c] = (m0 + r) * lda + kk;
        bRow[c] = (n0 + r) * ldb + kk;
    }
    const int aBase = (wm * 128 + (lane & 15)) * 64 + (lane >> 4) * 16;
    const int bBase = (wn * 64 + (lane & 15)) * 64 + (lane >> 4) * 16;

#define STG_A(pb, ks, kt) do { \
        gload_lds16(A + aRow[0] + (kt) + (ks) * 32, &As[pb][ks][st_idx[0]]); \
        gload_lds16(A + aRow[1] + (kt) + (ks) * 32, &As[pb][ks][st_idx[1]]); } while (0)
#define STG_B(pb, ks, kt) do { \
        gload_lds16(B + bRow[0] + (kt) + (ks) * 32, &Bs[pb][ks][st_idx[0]]); \
        gload_lds16(B + bRow[1] + (kt) + (ks) * 32, &Bs[pb][ks][st_idx[1]]); } while (0)
#define LD_A(dst, mf, ks, pb) do { int _o = aBase + (mf) * 1024; \
        _o ^= ((_o >> 9) & 1) << 5; \
        (dst) = *(const bf16x8*)((const char*)&As[pb][ks][0] + _o); } while (0)
#define LD_B(dst, nf, ks, pb) do { int _o = bBase + (nf) * 1024; \
        _o ^= ((_o >> 9) & 1) << 5; \
        (dst) = *(const bf16x8*)((const char*)&Bs[pb][ks][0] + _o); } while (0)
#define MM16(mb) do { \
        _Pragma("unroll") for (int mf = 0; mf < 4; ++mf) \
        _Pragma("unroll") for (int nf = 0; nf < 4; ++nf) \
            acc[(mb) + mf][nf] = __builtin_amdgcn_mfma_f32_16x16x32_bf16( \
                afr[mf], bfr[nf], acc[(mb) + mf][nf], 0, 0, 0); } while (0)

#define KTILE(pb, STG, ktn) do { \
        /* phase A: ksub0, rows 0-63 of wave */ \
        _Pragma("unroll") for (int i = 0; i < 4; ++i) LD_A(afr[i], i, 0, pb); \
        _Pragma("unroll") for (int i = 0; i < 4; ++i) LD_B(bfr[i], i, 0, pb); \
        if (STG) STG_A((pb) ^ 1, 0, ktn); \
        BAR; LGK0; SCHB; \
        __builtin_amdgcn_s_setprio(1); MM16(0); __builtin_amdgcn_s_setprio(0); \
        BAR; \
        /* phase B: ksub0, rows 64-127 */ \
        _Pragma("unroll") for (int i = 0; i < 4; ++i) LD_A(afr[i], 4 + i, 0, pb); \
        if (STG) STG_B((pb) ^ 1, 0, ktn); \
        BAR; LGK0; SCHB; \
        __builtin_amdgcn_s_setprio(1); MM16(4); __builtin_amdgcn_s_setprio(0); \
        if (STG) { VM4; } else { VM0; } \
        BAR; SCHB; \
        /* phase C: ksub1, rows 0-63 */ \
        _Pragma("unroll") for (int i = 0; i < 4; ++i) LD_A(afr[i], i, 1, pb); \
        _Pragma("unroll") for (int i = 0; i < 4; ++i) LD_B(bfr[i], i, 1, pb); \
        if (STG) STG_A((pb) ^ 1, 1, ktn); \
        BAR; LGK0; SCHB; \
        __builtin_amdgcn_s_setprio(1); MM16(0); __builtin_amdgcn_s_setprio(0); \
        BAR; \
        /* phase D: ksub1, rows 64-127 */ \
        _Pragma("unroll") for (int i = 0; i < 4; ++i) LD_A(afr[i], 4 + i, 1, pb); \
        if (STG) STG_B((pb) ^ 1, 1, ktn); \
        BAR; LGK0; SCHB; \
        __builtin_amdgcn_s_setprio(1); MM16(4); __builtin_amdgcn_s_setprio(0); \
        if (STG) { VM4; } \
        BAR; SCHB; \
    } while (0)

    f32x4 acc[8][4] = {};
    bf16x8 afr[4], bfr[4];

    // prologue: stage tile 0 (A.k0, B.k0, A.k1, B.k1) into buf 0
    STG_A(0, 0, 0); STG_B(0, 0, 0); STG_A(0, 1, 0); STG_B(0, 1, 0);
    VM4;  // A.k0 + B.k0 landed (this wave); barrier makes it collective
    BAR; SCHB;

    const int NT = K >> 6;
    int p = 0;
    for (int t = 0; t < NT - 1; ++t) {
        KTILE(p, 1, (t + 1) * 64);
        p ^= 1;
    }
    KTILE(p, 0, 0);

    // epilogue. C/D layout: col = lane&15, row = (lane>>4)*4 + j
    const int r_in = (lane >> 4) * 4;
    const int c_in = lane & 15;
    const float* rr = (EPI == 2) ? (rrowZ + (long)z * sR) : nullptr;
#pragma unroll
    for (int mf = 0; mf < 8; ++mf) {
#pragma unroll
        for (int nf = 0; nf < 4; ++nf) {
            const long cg = n0 + wn * 64 + nf * 16 + c_in;
#pragma unroll
            for (int j = 0; j < 4; ++j) {
                const long rg = m0 + wm * 128 + mf * 16 + r_in + j;
                float v = acc[mf][nf][j];
                if constexpr (EPI == 0) {
                    ((u16*)Cv)[(long)z * sC + rg * ldc + cg] = f2bf(v);
                } else if constexpr (EPI == 1) {
                    ((u16*)Cv)[(long)z * sC + rg * ldc + cg] = f2bf(__expf(v * scale));
                } else if constexpr (EPI == 2) {
                    ((u16*)Cv)[(long)z * sC + rg * ldc + cg] = f2bf(v * rr[rg]);
                } else {
                    ((float*)Cv)[(long)z * sC + rg * ldc + cg] = v + bias[cg];
                }
            }
        }
    }
#undef KTILE
#undef MM16
#undef LD_A
#undef LD_B
#undef STG_A
#undef STG_B
}

extern "C" void kernel_launch(void* const* d_in, const int* in_sizes, int n_in,
                              void* d_out, int out_size, void* d_ws, size_t ws_size,
                              hipStream_t stream) {
    (void)in_sizes; (void)n_in; (void)out_size;
    const int S = 4096;
    const long BS = 4L * S;  // 16384 tokens
    const float* x_f    = (const float*)d_in[0];  // [BS][2048]
    const float* Wqkv_f = (const float*)d_in[1];  // [2048][3072]
    const float* Wff_f  = (const float*)d_in[2];  // [1024][1024]
    const float* bff    = (const float*)d_in[3];  // [1024]
    float* out = (float*)d_out;                   // [BS][1024]

    // batched attention (z=4) needs 4x probs; fall back if ws too small
    const size_t need4 = 67108864UL + 12582912UL + 2097152UL + 100663296UL +
                         33554432UL + 4UL * 33554432UL + 33554432UL + 65536UL;
    const bool batched = ws_size >= need4;
    const int Z = batched ? 4 : 1;

    char* p = (char*)d_ws;
    u16* x_bf  = (u16*)p; p += BS * 2048 * 2;
    u16* WqkvT = (u16*)p; p += 3072L * 2048 * 2;
    u16* WffT  = (u16*)p; p += 1024L * 1024 * 2;
    u16* kqv   = (u16*)p; p += BS * 3072 * 2;
    u16* vT    = (u16*)p; p += 4L * 1024 * 4096 * 2;
    u16* probs = (u16*)p; p += (long)Z * 4096L * 4096 * 2;
    u16* attn  = (u16*)p; p += BS * 1024 * 2;
    float* rrow = (float*)p; p += (long)Z * 4096L * 4;

    // 1. conversions / weight transposes
    k_cvt_f32_bf16<<<dim3((unsigned)(BS * 2048 / 2048)), 256, 0, stream>>>(x_f, x_bf, BS * 2048);
    k_transpose_bf16<float><<<dim3(3072 / 32, 2048 / 32, 1), dim3(32, 8), 0, stream>>>(
        Wqkv_f, 3072, 0, WqkvT, 2048, 0, 2048, 3072);
    k_transpose_bf16<float><<<dim3(1024 / 32, 1024 / 32, 1), dim3(32, 8), 0, stream>>>(
        Wff_f, 1024, 0, WffT, 1024, 0, 1024, 1024);

    // 2. kqv = X @ W_qkv   [16384 x 3072], K=2048
    k_gemm8<0><<<dim3(3072 / 256, 16384 / 256, 1), 512, 0, stream>>>(
        x_bf, 2048, 0, WqkvT, 2048, 0, kqv, 3072, 0, 2048, 0.f, nullptr, 0, nullptr);

    // 3. transpose V (cols [2048,3072) of kqv) to [4][1024][4096]
    k_transpose_bf16<u16><<<dim3(1024 / 32, 4096 / 32, 4), dim3(32, 8), 0, stream>>>(
        kqv + 2048, 3072, (long)S * 3072, vT, 4096, 1024L * 4096, 4096, 1024);

    // 4. attention: probs = exp(Q K^T * scale); attn = (probs @ V) * (1/rowsum)
    const float scale = 0.08838834764831845f;  // 1/sqrt(128)
    for (int b = 0; b < 4; b += Z) {
        const u16* kbase = kqv + (long)b * S * 3072;  // k at +0, q at +1024
        k_gemm8<1><<<dim3(4096 / 256, 4096 / 256, Z), 512, 0, stream>>>(
            kbase + 1024, 3072, (long)S * 3072, kbase, 3072, (long)S * 3072,
            probs, 4096, (long)S * S, 1024, scale, nullptr, 0, nullptr);
        k_rowsum_recip<<<Z * 4096, 256, 0, stream>>>(probs, rrow, 4096);
        k_gemm8<2><<<dim3(1024 / 256, 4096 / 256, Z), 512, 0, stream>>>(
            probs, 4096, (long)S * S, vT + (long)b * 1024 * 4096, 4096, 1024L * 4096,
            attn + (long)b * S * 1024, 1024, (long)S * 1024,
            4096, 0.f, rrow, 4096, nullptr);
    }

    // 5. out = attn @ W_ff + b_ff  (fp32 output)
    k_gemm8<3><<<dim3(1024 / 256, 16384 / 256, 1), 512, 0, stream>>>(
        attn, 1024, 0, WffT, 1024, 0, out, 1024, 0, 1024, 0.f, nullptr, 0, bff);
}